// Round 1
// baseline (1144.147 us; speedup 1.0000x reference)
//
#include <hip/hip_runtime.h>

#define NN 20000
#define NE 320000

// ---- workspace layout (floats) ----
#define ACC_S_OFF 0
#define ACC_V_OFF (NN*64)
#define WT_OFF    (NN*256)

// transposed-weight sub-offsets (within wt)
#define O_ES1 0
#define O_ES2 8192
#define O_EV1 12288
#define O_NS1 16384
#define O_NS2 24576
#define O_NV1 28672
#define O_NV2 32768
#define O_NT1 36864
#define O_NT2 40960
#define O_C1  45056
#define O_C2  63488
#define WT_TOTAL 88064

#define NVOFF (NN*128)
#define NTOFF (NN*320)

__device__ __forceinline__ float silu_f(float x){ return x / (1.f + __expf(-x)); }
__device__ __forceinline__ float sigm_f(float x){ return 1.f / (1.f + __expf(-x)); }

#define FMA4(A,B,C,D,X,W) { (A) += (X)*(W).x; (B) += (X)*(W).y; (C) += (X)*(W).z; (D) += (X)*(W).w; }

// 4 rows x 4 channels x 4 k-steps: 64 FMAs per 8 vector loads
__device__ __forceinline__ void tile16(const float* __restrict__ xr, const int XS,
                                       const float* __restrict__ wr, const int WS,
                                       float (&a)[16])
{
  const float4 x0 = *(const float4*)(xr);
  const float4 x1 = *(const float4*)(xr + XS);
  const float4 x2 = *(const float4*)(xr + 2*XS);
  const float4 x3 = *(const float4*)(xr + 3*XS);
  float4 w;
  w = *(const float4*)(wr);
  FMA4(a[0],a[1],a[2],a[3],x0.x,w) FMA4(a[4],a[5],a[6],a[7],x1.x,w)
  FMA4(a[8],a[9],a[10],a[11],x2.x,w) FMA4(a[12],a[13],a[14],a[15],x3.x,w)
  w = *(const float4*)(wr + WS);
  FMA4(a[0],a[1],a[2],a[3],x0.y,w) FMA4(a[4],a[5],a[6],a[7],x1.y,w)
  FMA4(a[8],a[9],a[10],a[11],x2.y,w) FMA4(a[12],a[13],a[14],a[15],x3.y,w)
  w = *(const float4*)(wr + 2*WS);
  FMA4(a[0],a[1],a[2],a[3],x0.z,w) FMA4(a[4],a[5],a[6],a[7],x1.z,w)
  FMA4(a[8],a[9],a[10],a[11],x2.z,w) FMA4(a[12],a[13],a[14],a[15],x3.z,w)
  w = *(const float4*)(wr + 3*WS);
  FMA4(a[0],a[1],a[2],a[3],x0.w,w) FMA4(a[4],a[5],a[6],a[7],x1.w,w)
  FMA4(a[8],a[9],a[10],a[11],x2.w,w) FMA4(a[12],a[13],a[14],a[15],x3.w,w)
}

__device__ __forceinline__ void tile8(const float* __restrict__ xr, const int XS,
                                      const float* __restrict__ wr, const int WS,
                                      float (&a)[8])
{
  const float4 x0 = *(const float4*)(xr);
  const float4 x1 = *(const float4*)(xr + XS);
  const float4 x2 = *(const float4*)(xr + 2*XS);
  const float4 x3 = *(const float4*)(xr + 3*XS);
  float2 w;
  w = *(const float2*)(wr);
  a[0]+=x0.x*w.x; a[1]+=x0.x*w.y; a[2]+=x1.x*w.x; a[3]+=x1.x*w.y;
  a[4]+=x2.x*w.x; a[5]+=x2.x*w.y; a[6]+=x3.x*w.x; a[7]+=x3.x*w.y;
  w = *(const float2*)(wr + WS);
  a[0]+=x0.y*w.x; a[1]+=x0.y*w.y; a[2]+=x1.y*w.x; a[3]+=x1.y*w.y;
  a[4]+=x2.y*w.x; a[5]+=x2.y*w.y; a[6]+=x3.y*w.x; a[7]+=x3.y*w.y;
  w = *(const float2*)(wr + 2*WS);
  a[0]+=x0.z*w.x; a[1]+=x0.z*w.y; a[2]+=x1.z*w.x; a[3]+=x1.z*w.y;
  a[4]+=x2.z*w.x; a[5]+=x2.z*w.y; a[6]+=x3.z*w.x; a[7]+=x3.z*w.y;
  w = *(const float2*)(wr + 3*WS);
  a[0]+=x0.w*w.x; a[1]+=x0.w*w.y; a[2]+=x1.w*w.x; a[3]+=x1.w*w.y;
  a[4]+=x2.w*w.x; a[5]+=x2.w*w.y; a[6]+=x3.w*w.x; a[7]+=x3.w*w.y;
}

// ---------------- weight transpose prep ----------------
__global__ void k_prep(const float* __restrict__ s0,const float* __restrict__ s1,
  const float* __restrict__ s2,const float* __restrict__ s3,const float* __restrict__ s4,
  const float* __restrict__ s5,const float* __restrict__ s6,const float* __restrict__ s7,
  const float* __restrict__ s8,const float* __restrict__ s9,const float* __restrict__ s10,
  float* __restrict__ wt)
{
  int i = blockIdx.x*256 + threadIdx.x;
  if (i >= WT_TOTAL) return;
  if (i < 8192) { wt[O_ES1 + (i&127)*64 + (i>>7)] = s0[i]; return; } i -= 8192;
  if (i < 4096) { wt[O_ES2 + (i&63)*64 + (i>>6)] = s1[i]; return; } i -= 4096;
  if (i < 4096) { wt[O_EV1 + (i&63)*64 + (i>>6)] = s2[i]; return; } i -= 4096;
  if (i < 8192) { wt[O_NS1 + (i&127)*64 + (i>>7)] = s3[i]; return; } i -= 8192;
  if (i < 4096) { wt[O_NS2 + (i&63)*64 + (i>>6)] = s4[i]; return; } i -= 4096;
  if (i < 4096) { wt[O_NV1 + (i&63)*64 + (i>>6)] = s5[i]; return; } i -= 4096;
  if (i < 4096) { wt[O_NV2 + (i&63)*64 + (i>>6)] = s6[i]; return; } i -= 4096;
  if (i < 4096) { wt[O_NT1 + (i&63)*64 + (i>>6)] = s7[i]; return; } i -= 4096;
  if (i < 4096) { wt[O_NT2 + (i&63)*64 + (i>>6)] = s8[i]; return; } i -= 4096;
  if (i < 18432) { int r = i/192, c = i - r*192; wt[O_C1 + c*96 + r] = s9[i]; return; } i -= 18432;
  { int r = i/96, c = i - r*96; wt[O_C2 + c*256 + r] = s10[i]; }
}

// ---------------- edge kernel ----------------
// block = 256 threads = 4 waves; block tile = 64 edges; wave tile = 16 edges x 64 ch
__global__ __launch_bounds__(256, 4) void k_edge(
    const float* __restrict__ h_es, const float* __restrict__ h_ev,
    const int* __restrict__ idx1, const int* __restrict__ idx2,
    const float* __restrict__ wt,
    const float* __restrict__ bes1, const float* __restrict__ bes2,
    float* __restrict__ acc_s, float* __restrict__ acc_v)
{
  __shared__ float xb[64*68];   // activations tile [row][68]
  __shared__ float wb[64*68];   // weight chunk [k][68]
  __shared__ float st[64*68];   // t1 / es / ev stash [edge][68]
  __shared__ int sidx[128];
  const int tid  = threadIdx.x;
  const int lane = tid & 63;
  const int wv   = tid >> 6;
  const int g    = lane >> 4;
  const int cs   = lane & 15;
  const int ew   = wv*16;
  const int er   = ew + g*4;
  const int e0   = blockIdx.x * 64;

  if (tid < 64) sidx[tid] = idx1[e0 + tid];
  else if (tid < 128) sidx[tid] = idx2[e0 + tid - 64];

  float acc[16];
  #pragma unroll
  for (int t=0;t<16;t++) acc[t]=0.f;

  // ---- t1 = silu(h_es @ Wes1t + bes1), K=128 in 2 chunks ----
  for (int kc=0; kc<2; kc++) {
    __syncthreads();
    #pragma unroll
    for (int it=0; it<4; it++) {
      int flat = it*256 + tid;
      int k4 = flat & 15, e = flat >> 4;
      *(float4*)&xb[e*68 + k4*4] = *(const float4*)&h_es[(e0+e)*128 + kc*64 + k4*4];
      *(float4*)&wb[e*68 + k4*4] = *(const float4*)&wt[O_ES1 + (kc*64+e)*64 + k4*4];
    }
    __syncthreads();
    #pragma unroll 4
    for (int k4=0;k4<16;k4++)
      tile16(&xb[er*68 + k4*4], 68, &wb[(k4*4)*68 + cs*4], 68, acc);
  }
  {
    const float4 bb = *(const float4*)&bes1[cs*4];
    #pragma unroll
    for (int i=0;i<4;i++) {
      float4 v;
      v.x = silu_f(acc[i*4+0] + bb.x); v.y = silu_f(acc[i*4+1] + bb.y);
      v.z = silu_f(acc[i*4+2] + bb.z); v.w = silu_f(acc[i*4+3] + bb.w);
      *(float4*)&st[(er+i)*68 + cs*4] = v;
    }
  }
  // ---- es = t1 @ Wes2t + bes2 ----
  __syncthreads();
  #pragma unroll
  for (int it=0; it<4; it++) {
    int flat = it*256 + tid;
    int k4 = flat & 15, e = flat >> 4;
    *(float4*)&wb[e*68 + k4*4] = *(const float4*)&wt[O_ES2 + e*64 + k4*4];
  }
  __syncthreads();
  float a2[16];
  #pragma unroll
  for (int t=0;t<16;t++) a2[t]=0.f;
  #pragma unroll 4
  for (int k4=0;k4<16;k4++)
    tile16(&st[er*68 + k4*4], 68, &wb[(k4*4)*68 + cs*4], 68, a2);
  {
    const float4 bb = *(const float4*)&bes2[cs*4];
    #pragma unroll
    for (int i=0;i<4;i++) {
      float4 v;
      v.x = a2[i*4+0]+bb.x; v.y = a2[i*4+1]+bb.y; v.z = a2[i*4+2]+bb.z; v.w = a2[i*4+3]+bb.w;
      *(float4*)&st[(er+i)*68 + cs*4] = v;
    }
  }
  // ---- scatter es (64 consecutive floats per atomic instruction) ----
  for (int e=0;e<16;e++) {
    float v = st[(ew+e)*68 + lane];
    int i1 = sidx[ew+e], i2 = sidx[64+ew+e];
    unsafeAtomicAdd(&acc_s[i1*64 + lane], v);
    unsafeAtomicAdd(&acc_s[i2*64 + lane], v);
  }
  // ---- ev1 = h_ev @ Wev1t, per d, + scatter ----
  __syncthreads();
  #pragma unroll
  for (int it=0; it<4; it++) {
    int flat = it*256 + tid;
    int k4 = flat & 15, e = flat >> 4;
    *(float4*)&wb[e*68 + k4*4] = *(const float4*)&wt[O_EV1 + e*64 + k4*4];
  }
  __syncthreads();
  for (int d=0; d<3; d++) {
    __syncthreads();
    #pragma unroll
    for (int it=0; it<4; it++) {
      int flat = it*256 + tid;
      int k4 = flat & 15, e = flat >> 4;
      *(float4*)&xb[e*68 + k4*4] = *(const float4*)&h_ev[(e0+e)*192 + d*64 + k4*4];
    }
    __syncthreads();
    float a[16];
    #pragma unroll
    for (int t=0;t<16;t++) a[t]=0.f;
    #pragma unroll 4
    for (int k4=0;k4<16;k4++)
      tile16(&xb[er*68 + k4*4], 68, &wb[(k4*4)*68 + cs*4], 68, a);
    #pragma unroll
    for (int i=0;i<4;i++) {
      float4 v; v.x=a[i*4+0]; v.y=a[i*4+1]; v.z=a[i*4+2]; v.w=a[i*4+3];
      *(float4*)&st[(er+i)*68 + cs*4] = v;
    }
    for (int e=0;e<16;e++) {
      float v = st[(ew+e)*68 + lane];
      int i1 = sidx[ew+e], i2 = sidx[64+ew+e];
      unsafeAtomicAdd(&acc_v[(i1*3+d)*64 + lane], v);
      unsafeAtomicAdd(&acc_v[(i2*3+d)*64 + lane], v);
    }
  }
}

// ---------------- node kernel ----------------
// block = 64 threads = 1 wave; tile = 16 nodes x 64 ch (4x4 per lane)
__global__ __launch_bounds__(64, 4) void k_node(
    const float* __restrict__ h_ns, const float* __restrict__ h_nv, const float* __restrict__ h_nt,
    const float* __restrict__ wt, const float* __restrict__ acc_s, const float* __restrict__ acc_v,
    const float* __restrict__ bns1, const float* __restrict__ bns2,
    const float* __restrict__ bc1, const float* __restrict__ bc2,
    float* __restrict__ out)
{
  __shared__ float xb[16*132];   // K=128 staging
  __shared__ float sb[16*68];    // t1 / 64-k slices
  __shared__ float cat[16*196];  // h_cat [n][192+pad]
  __shared__ float c1[16*100];   // c1 [n][96+pad]
  const int lane = threadIdx.x;
  const int g = lane >> 4, cs = lane & 15;
  const int n0 = blockIdx.x * 16;
  const int nr = g*4;

  // ---- phase A: hs + acc_s ----
  #pragma unroll
  for (int it=0; it<8; it++) {
    int flat = it*64 + lane;
    int k4 = flat & 31, n = flat >> 5;
    *(float4*)&xb[n*132 + k4*4] = *(const float4*)&h_ns[(n0+n)*128 + k4*4];
  }
  __syncthreads();
  float a1[16];
  #pragma unroll
  for (int t=0;t<16;t++) a1[t]=0.f;
  #pragma unroll 4
  for (int k4=0;k4<32;k4++)
    tile16(&xb[nr*132 + k4*4], 132, &wt[O_NS1 + (k4*4)*64 + cs*4], 64, a1);
  {
    const float4 bb = *(const float4*)&bns1[cs*4];
    #pragma unroll
    for (int i=0;i<4;i++) {
      float4 v;
      v.x = silu_f(a1[i*4+0]+bb.x); v.y = silu_f(a1[i*4+1]+bb.y);
      v.z = silu_f(a1[i*4+2]+bb.z); v.w = silu_f(a1[i*4+3]+bb.w);
      *(float4*)&sb[(nr+i)*68 + cs*4] = v;
    }
  }
  __syncthreads();
  float a2[16];
  #pragma unroll
  for (int t=0;t<16;t++) a2[t]=0.f;
  #pragma unroll 4
  for (int k4=0;k4<16;k4++)
    tile16(&sb[nr*68 + k4*4], 68, &wt[O_NS2 + (k4*4)*64 + cs*4], 64, a2);
  {
    const float4 bb = *(const float4*)&bns2[cs*4];
    #pragma unroll
    for (int i=0;i<4;i++) {
      float4 as = *(const float4*)&acc_s[(n0+nr+i)*64 + cs*4];
      float4 v;
      v.x = a2[i*4+0]+bb.x+as.x; v.y = a2[i*4+1]+bb.y+as.y;
      v.z = a2[i*4+2]+bb.z+as.z; v.w = a2[i*4+3]+bb.w+as.w;
      *(float4*)&cat[(nr+i)*196 + cs*4] = v;
    }
  }
  // ---- phase B: nv norm ----
  float nm[16];
  #pragma unroll
  for (int t=0;t<16;t++) nm[t]=0.f;
  for (int d=0; d<3; d++) {
    __syncthreads();
    #pragma unroll
    for (int it=0; it<4; it++) {
      int flat = it*64 + lane;
      int k4 = flat & 15, n = flat >> 4;
      *(float4*)&sb[n*68 + k4*4] = *(const float4*)&h_nv[((n0+n)*3+d)*64 + k4*4];
    }
    __syncthreads();
    float a[16];
    #pragma unroll
    for (int t=0;t<16;t++) a[t]=0.f;
    #pragma unroll 4
    for (int k4=0;k4<16;k4++)
      tile16(&sb[nr*68 + k4*4], 68, &wt[O_NV1 + (k4*4)*64 + cs*4], 64, a);
    #pragma unroll
    for (int i=0;i<4;i++) {
      float4 av = *(const float4*)&acc_v[((n0+nr+i)*3+d)*64 + cs*4];
      a[i*4+0]+=av.x; a[i*4+1]+=av.y; a[i*4+2]+=av.z; a[i*4+3]+=av.w;
    }
    #pragma unroll
    for (int t=0;t<16;t++) nm[t] += a[t]*a[t];
  }
  #pragma unroll
  for (int i=0;i<4;i++) {
    float4 v;
    v.x = sqrtf(nm[i*4+0]); v.y = sqrtf(nm[i*4+1]); v.z = sqrtf(nm[i*4+2]); v.w = sqrtf(nm[i*4+3]);
    *(float4*)&cat[(nr+i)*196 + 64 + cs*4] = v;
  }
  // ---- phase C: nt norm ----
  #pragma unroll
  for (int t=0;t<16;t++) nm[t]=0.f;
  for (int dd=0; dd<9; dd++) {
    __syncthreads();
    #pragma unroll
    for (int it=0; it<4; it++) {
      int flat = it*64 + lane;
      int k4 = flat & 15, n = flat >> 4;
      *(float4*)&sb[n*68 + k4*4] = *(const float4*)&h_nt[((n0+n)*9+dd)*64 + k4*4];
    }
    __syncthreads();
    float a[16];
    #pragma unroll
    for (int t=0;t<16;t++) a[t]=0.f;
    #pragma unroll 4
    for (int k4=0;k4<16;k4++)
      tile16(&sb[nr*68 + k4*4], 68, &wt[O_NT1 + (k4*4)*64 + cs*4], 64, a);
    #pragma unroll
    for (int t=0;t<16;t++) nm[t] += a[t]*a[t];
  }
  #pragma unroll
  for (int i=0;i<4;i++) {
    float4 v;
    v.x = sqrtf(nm[i*4+0]); v.y = sqrtf(nm[i*4+1]); v.z = sqrtf(nm[i*4+2]); v.w = sqrtf(nm[i*4+3]);
    *(float4*)&cat[(nr+i)*196 + 128 + cs*4] = v;
  }
  __syncthreads();
  // ---- MLP: c1 = silu(h_cat @ Wc1t + bc1) ----
  float ca[16];
  #pragma unroll
  for (int t=0;t<16;t++) ca[t]=0.f;
  #pragma unroll 4
  for (int k4=0;k4<48;k4++)
    tile16(&cat[nr*196 + k4*4], 196, &wt[O_C1 + (k4*4)*96 + cs*4], 96, ca);
  {
    const float4 bb = *(const float4*)&bc1[cs*4];
    #pragma unroll
    for (int i=0;i<4;i++) {
      float4 v;
      v.x = silu_f(ca[i*4+0]+bb.x); v.y = silu_f(ca[i*4+1]+bb.y);
      v.z = silu_f(ca[i*4+2]+bb.z); v.w = silu_f(ca[i*4+3]+bb.w);
      *(float4*)&c1[(nr+i)*100 + cs*4] = v;
    }
  }
  float cb[8];
  #pragma unroll
  for (int t=0;t<8;t++) cb[t]=0.f;
  #pragma unroll 4
  for (int k4=0;k4<48;k4++)
    tile8(&cat[nr*196 + k4*4], 196, &wt[O_C1 + (k4*4)*96 + 64 + cs*2], 96, cb);
  {
    const float2 bb = *(const float2*)&bc1[64 + cs*2];
    #pragma unroll
    for (int i=0;i<4;i++) {
      c1[(nr+i)*100 + 64 + cs*2 + 0] = silu_f(cb[i*2+0]+bb.x);
      c1[(nr+i)*100 + 64 + cs*2 + 1] = silu_f(cb[i*2+1]+bb.y);
    }
  }
  __syncthreads();
  // ---- out passes p=0,1: ns_out ----
  for (int p=0;p<2;p++) {
    float o[16];
    #pragma unroll
    for (int t=0;t<16;t++) o[t]=0.f;
    #pragma unroll 4
    for (int k4=0;k4<24;k4++)
      tile16(&c1[nr*100 + k4*4], 100, &wt[O_C2 + (k4*4)*256 + p*64 + cs*4], 256, o);
    const float4 bb = *(const float4*)&bc2[p*64 + cs*4];
    #pragma unroll
    for (int i=0;i<4;i++) {
      float4 r = *(const float4*)&h_ns[(n0+nr+i)*128 + p*64 + cs*4];
      float4 v;
      v.x = o[i*4+0]+bb.x+r.x; v.y = o[i*4+1]+bb.y+r.y;
      v.z = o[i*4+2]+bb.z+r.z; v.w = o[i*4+3]+bb.w+r.w;
      *(float4*)&out[(n0+nr+i)*128 + p*64 + cs*4] = v;
    }
  }
  // ---- p=2: nv gates, recompute nv2, write nv_out ----
  float gt[16];
  {
    float o[16];
    #pragma unroll
    for (int t=0;t<16;t++) o[t]=0.f;
    #pragma unroll 4
    for (int k4=0;k4<24;k4++)
      tile16(&c1[nr*100 + k4*4], 100, &wt[O_C2 + (k4*4)*256 + 128 + cs*4], 256, o);
    const float4 bb = *(const float4*)&bc2[128 + cs*4];
    #pragma unroll
    for (int i=0;i<4;i++) {
      gt[i*4+0]=sigm_f(o[i*4+0]+bb.x); gt[i*4+1]=sigm_f(o[i*4+1]+bb.y);
      gt[i*4+2]=sigm_f(o[i*4+2]+bb.z); gt[i*4+3]=sigm_f(o[i*4+3]+bb.w);
    }
  }
  for (int d=0;d<3;d++) {
    __syncthreads();
    #pragma unroll
    for (int it=0; it<4; it++) {
      int flat = it*64 + lane;
      int k4 = flat & 15, n = flat >> 4;
      *(float4*)&sb[n*68 + k4*4] = *(const float4*)&h_nv[((n0+n)*3+d)*64 + k4*4];
    }
    __syncthreads();
    float a[16];
    #pragma unroll
    for (int t=0;t<16;t++) a[t]=0.f;
    #pragma unroll 4
    for (int k4=0;k4<16;k4++)
      tile16(&sb[nr*68 + k4*4], 68, &wt[O_NV2 + (k4*4)*64 + cs*4], 64, a);
    #pragma unroll
    for (int i=0;i<4;i++) {
      float4 hv = *(const float4*)&sb[(nr+i)*68 + cs*4];
      float4 v;
      v.x = gt[i*4+0]*a[i*4+0]+hv.x; v.y = gt[i*4+1]*a[i*4+1]+hv.y;
      v.z = gt[i*4+2]*a[i*4+2]+hv.z; v.w = gt[i*4+3]*a[i*4+3]+hv.w;
      *(float4*)&out[NVOFF + ((n0+nr+i)*3+d)*64 + cs*4] = v;
    }
  }
  // ---- p=3: nt gates, recompute nt2, write nt_out ----
  {
    float o[16];
    #pragma unroll
    for (int t=0;t<16;t++) o[t]=0.f;
    #pragma unroll 4
    for (int k4=0;k4<24;k4++)
      tile16(&c1[nr*100 + k4*4], 100, &wt[O_C2 + (k4*4)*256 + 192 + cs*4], 256, o);
    const float4 bb = *(const float4*)&bc2[192 + cs*4];
    #pragma unroll
    for (int i=0;i<4;i++) {
      gt[i*4+0]=sigm_f(o[i*4+0]+bb.x); gt[i*4+1]=sigm_f(o[i*4+1]+bb.y);
      gt[i*4+2]=sigm_f(o[i*4+2]+bb.z); gt[i*4+3]=sigm_f(o[i*4+3]+bb.w);
    }
  }
  for (int dd=0;dd<9;dd++) {
    __syncthreads();
    #pragma unroll
    for (int it=0; it<4; it++) {
      int flat = it*64 + lane;
      int k4 = flat & 15, n = flat >> 4;
      *(float4*)&sb[n*68 + k4*4] = *(const float4*)&h_nt[((n0+n)*9+dd)*64 + k4*4];
    }
    __syncthreads();
    float a[16];
    #pragma unroll
    for (int t=0;t<16;t++) a[t]=0.f;
    #pragma unroll 4
    for (int k4=0;k4<16;k4++)
      tile16(&sb[nr*68 + k4*4], 68, &wt[O_NT2 + (k4*4)*64 + cs*4], 64, a);
    #pragma unroll
    for (int i=0;i<4;i++) {
      float4 hv = *(const float4*)&sb[(nr+i)*68 + cs*4];
      float4 v;
      v.x = gt[i*4+0]*a[i*4+0]+hv.x; v.y = gt[i*4+1]*a[i*4+1]+hv.y;
      v.z = gt[i*4+2]*a[i*4+2]+hv.z; v.w = gt[i*4+3]*a[i*4+3]+hv.w;
      *(float4*)&out[NTOFF + ((n0+nr+i)*9+dd)*64 + cs*4] = v;
    }
  }
}

extern "C" void kernel_launch(void* const* d_in, const int* in_sizes, int n_in,
                              void* d_out, int out_size, void* d_ws, size_t ws_size,
                              hipStream_t stream) {
  (void)in_sizes; (void)n_in; (void)out_size; (void)ws_size;
  const float* h_ns = (const float*)d_in[0];
  const float* h_nv = (const float*)d_in[1];
  const float* h_nt = (const float*)d_in[2];
  const float* h_es = (const float*)d_in[3];
  const float* h_ev = (const float*)d_in[4];
  const int*   idx1 = (const int*)d_in[5];
  const int*   idx2 = (const int*)d_in[6];
  const float* Wns1=(const float*)d_in[7];  const float* bns1=(const float*)d_in[8];
  const float* Wns2=(const float*)d_in[9];  const float* bns2=(const float*)d_in[10];
  const float* Wes1=(const float*)d_in[11]; const float* bes1=(const float*)d_in[12];
  const float* Wes2=(const float*)d_in[13]; const float* bes2=(const float*)d_in[14];
  const float* Wnv1=(const float*)d_in[15]; const float* Wnv2=(const float*)d_in[16];
  const float* Wev1=(const float*)d_in[17];
  const float* Wnt1=(const float*)d_in[18]; const float* Wnt2=(const float*)d_in[19];
  const float* Wc1 =(const float*)d_in[20]; const float* bc1 =(const float*)d_in[21];
  const float* Wc2 =(const float*)d_in[22]; const float* bc2 =(const float*)d_in[23];
  float* ws = (float*)d_ws;
  float* acc_s = ws + ACC_S_OFF;
  float* acc_v = ws + ACC_V_OFF;
  float* wt    = ws + WT_OFF;
  float* out   = (float*)d_out;

  hipMemsetAsync(ws, 0, (size_t)(NN*256)*sizeof(float), stream);
  k_prep<<<(WT_TOTAL+255)/256, 256, 0, stream>>>(Wes1,Wes2,Wev1,Wns1,Wns2,Wnv1,Wnv2,Wnt1,Wnt2,Wc1,Wc2, wt);
  k_edge<<<NE/64, 256, 0, stream>>>(h_es,h_ev,idx1,idx2,wt,bes1,bes2,acc_s,acc_v);
  k_node<<<NN/16, 64, 0, stream>>>(h_ns,h_nv,h_nt,wt,acc_s,acc_v,bns1,bns2,bc1,bc2,out);
}